// Round 5
// baseline (766.149 us; speedup 1.0000x reference)
//
#include <hip/hip_runtime.h>
#include <hip/hip_fp16.h>

#define N_TOK 65536
#define K_EMB 8192
#define D_DIM 256
#define LIST_CAP 12288
#define CAND_CAP 16384

typedef unsigned short u16;
typedef unsigned int u32;
typedef unsigned long long u64;
typedef _Float16 f16x8 __attribute__((ext_vector_type(8)));
typedef float f32x16 __attribute__((ext_vector_type(16)));

__device__ __forceinline__ u16 f2h(float f) {   // f32 -> f16 bits, RNE
  union { _Float16 h; u16 u; } c; c.h = (_Float16)f; return c.u;
}
__device__ __forceinline__ f16x8 as_f16x8(uint4 v) {
  union { uint4 u; f16x8 h; } c; c.u = v; return c.h;
}
__device__ __forceinline__ void gld_lds16(const u16* g, u16* l) {
  __builtin_amdgcn_global_load_lds((const __attribute__((address_space(1))) void*)g,
                                   (__attribute__((address_space(3))) void*)l,
                                   16, 0, 0);
}

// ---------------------------------------------------------------- prep
// ehh[k][d]=f16(emb*2^19); e2f[k]=fl32(sum e^2, f64); e2h[k]=f16(-e2*2^24).
// Zeroes both atomic counters (fresh every call -> graph-replay safe).
__global__ void vq_prep(const float* __restrict__ emb, u16* __restrict__ ehh,
                        float* __restrict__ e2f, u16* __restrict__ e2h,
                        int* __restrict__ count, int* __restrict__ candcount) {
  if (blockIdx.x == 0 && threadIdx.x == 0) { *count = 0; *candcount = 0; }
  const int w = threadIdx.x >> 6, lane = threadIdx.x & 63;
  const int k = blockIdx.x * 4 + w;
  const float4 v = ((const float4*)(emb + (size_t)k * D_DIM))[lane];
  uint2 p;
  p.x = (u32)f2h(v.x * 524288.0f) | ((u32)f2h(v.y * 524288.0f) << 16);
  p.y = (u32)f2h(v.z * 524288.0f) | ((u32)f2h(v.w * 524288.0f) << 16);
  ((uint2*)(ehh + (size_t)k * D_DIM))[lane] = p;
  double s = (double)v.x * v.x + (double)v.y * v.y +
             (double)v.z * v.z + (double)v.w * v.w;
  #pragma unroll
  for (int off = 32; off > 0; off >>= 1) s += __shfl_down(s, off);
  if (lane == 0) { e2f[k] = (float)s; e2h[k] = f2h(-(float)s * 16777216.0f); }
}

// ---------------------------------------------------------------- phase 1
// Round-4 counted-vmcnt pipeline (4 LDS buffers, stage(t+3), vmcnt(8) never
// 0 in-loop, e2h in LDS, zero global loads in the main loop) PLUS deferred
// top-2 scan: tile t's MFMA chain issues while tile t-1's scan VALU runs in
// its issue gaps (scan is order-independent: keys distinct). Dual named
// accumulator pairs (rule: static indexing only). __launch_bounds__(512,1)
// -> 256-VGPR cap: zres 128 + 4x16 acc + temps fits WITHOUT spilling (the
// (512,2) cap of 128 was what spilled round-4; 2nd arg = min blocks/CU).
__launch_bounds__(512, 1)
__global__ void vq_phase1(const float* __restrict__ zg, const u16* __restrict__ ehh,
                          const u16* __restrict__ e2h, float* __restrict__ z2f,
                          int* __restrict__ idx1_ws, int* __restrict__ thrbuf,
                          u64* __restrict__ refbuf, int* __restrict__ list,
                          int* __restrict__ count) {
  __shared__ u16 lds[4][16384];    // 4 x 32 KB tile buffers (64 k-rows each)
  __shared__ u16 e2l[8192];        // all of e2h (16 KB)
  __shared__ float z2s[256];       // per-row z2 (fused vq_z2)

  const int tid  = threadIdx.x;
  const int w    = tid >> 6;
  const int lane = tid & 63;
  const int q    = w & 1;          // k-substrip (32 k rows)
  const int g    = w >> 1;         // n-group (64 rows = 2 strips x 32)
  const int col  = lane & 31;
  const int h    = lane >> 5;
  const int n0   = blockIdx.x * 256 + g * 64;

  // e2h -> LDS: 16 chunks of 1 KB, 2 per wave (issued first -> oldest VMEM)
  #pragma unroll
  for (int i = 0; i < 2; ++i) {
    int pp = w * 2 + i;
    gld_lds16(e2h + pp * 512 + lane * 8, &e2l[pp * 512]);
  }

  // z fragments (f16(z*64), 128 VGPRs) + fused z2 (f64 row norm)
  uint4 zres0[16], zres1[16];
  double zs0 = 0.0, zs1 = 0.0;
#define P1_ZLOAD(ZR, ZS, S) { \
    const float4* zp_ = (const float4*)(zg + (size_t)(n0 + (S) * 32 + col) * D_DIM); \
    _Pragma("unroll") \
    for (int c = 0; c < 16; ++c) { \
      float4 a_ = zp_[c * 4 + h * 2]; \
      float4 b_ = zp_[c * 4 + h * 2 + 1]; \
      ZS += (double)a_.x * a_.x + (double)a_.y * a_.y + \
            (double)a_.z * a_.z + (double)a_.w * a_.w; \
      ZS += (double)b_.x * b_.x + (double)b_.y * b_.y + \
            (double)b_.z * b_.z + (double)b_.w * b_.w; \
      uint4 u_; \
      u_.x = (u32)f2h(a_.x * 64.0f) | ((u32)f2h(a_.y * 64.0f) << 16); \
      u_.y = (u32)f2h(a_.z * 64.0f) | ((u32)f2h(a_.w * 64.0f) << 16); \
      u_.z = (u32)f2h(b_.x * 64.0f) | ((u32)f2h(b_.y * 64.0f) << 16); \
      u_.w = (u32)f2h(b_.z * 64.0f) | ((u32)f2h(b_.w * 64.0f) << 16); \
      ZR[c] = u_; \
    } }
  P1_ZLOAD(zres0, zs0, 0);
  P1_ZLOAD(zres1, zs1, 1);
#undef P1_ZLOAD
  zs0 += __shfl_xor(zs0, 32);      // combine half-rows (h=0 + h=1)
  zs1 += __shfl_xor(zs1, 32);
  if (lane < 32) {                 // q=0,1 waves write identical bits
    z2s[g * 64 + col]      = (float)zs0;  z2f[n0 + col]      = (float)zs0;
    z2s[g * 64 + 32 + col] = (float)zs1;  z2f[n0 + 32 + col] = (float)zs1;
  }

  uint4 bone = {0, 0, 0, 0};
  if (h == 0) bone.x = 0x3C00u;    // f16 1.0 at kk=0 (e2-fold B-fragment)

  int m1[2] = {(int)0x80000000, (int)0x80000000};
  int m2[2] = {(int)0x80000000, (int)0x80000000};
  f32x16 accA0 = {}, accA1 = {}, accB0 = {}, accB1 = {};

#define P1_STAGE(T) { \
    _Pragma("unroll") \
    for (int i = 0; i < 4; ++i) { \
      int pp_ = w * 4 + i, qs_ = pp_ >> 4, cs_ = pp_ & 15; \
      gld_lds16(ehh + (size_t)((T) * 64 + qs_ * 32 + col) * D_DIM + cs_ * 16 + h * 8, \
                &lds[(T) & 3][qs_ * 8192 + cs_ * 512]); \
    } }
#define P1_COMPUTE(ACC0, ACC1, T) { \
    const u16* lb_ = &lds[(T) & 3][q * 8192]; \
    uint4 ea_ = {0, 0, 0, 0}; \
    if (h == 0) ea_.x = (u32)e2l[(T) * 64 + q * 32 + col]; \
    _Pragma("unroll") \
    for (int c = 0; c < 16; ++c) { \
      f16x8 af_ = as_f16x8(*(const uint4*)(lb_ + c * 512 + lane * 8)); \
      ACC0 = __builtin_amdgcn_mfma_f32_32x32x16_f16(af_, as_f16x8(zres0[c]), ACC0, 0, 0, 0); \
      ACC1 = __builtin_amdgcn_mfma_f32_32x32x16_f16(af_, as_f16x8(zres1[c]), ACC1, 0, 0, 0); \
    } \
    ACC0 = __builtin_amdgcn_mfma_f32_32x32x16_f16(as_f16x8(ea_), as_f16x8(bone), ACC0, 0, 0, 0); \
    ACC1 = __builtin_amdgcn_mfma_f32_32x32x16_f16(as_f16x8(ea_), as_f16x8(bone), ACC1, 0, 0, 0); }
#define P1_SCAN(ACC0, ACC1, T) { \
    const int bi_ = 4095 - (T) * 32 - q * 16; \
    _Pragma("unroll") \
    for (int r = 0; r < 16; ++r) { \
      int ka_ = ((int)ACC0[r] << 12) + (bi_ - r); \
      m2[0] = max(m2[0], min(m1[0], ka_)); \
      m1[0] = max(m1[0], ka_); \
      int kb_ = ((int)ACC1[r] << 12) + (bi_ - r); \
      m2[1] = max(m2[1], min(m1[1], kb_)); \
      m1[1] = max(m1[1], kb_); \
    } }
#define P1_ZERO(ACC0, ACC1) { \
    _Pragma("unroll") \
    for (int r = 0; r < 16; ++r) { ACC0[r] = 0.0f; ACC1[r] = 0.0f; } }
#define P1_WAIT(N) \
    asm volatile("s_waitcnt vmcnt(" #N ")" ::: "memory"); \
    asm volatile("s_barrier" ::: "memory");

  P1_STAGE(0); P1_STAGE(1); P1_STAGE(2);    // depth-3 prologue
  // steady state: before each WAIT, outstanding = {e2l+}3 stages (12-14 ops);
  // vmcnt(8) completes exactly the oldest stage; 2 newer stages stay in
  // flight ACROSS the barrier (T4: never drain to 0 in-loop).
  P1_WAIT(8); P1_STAGE(3);
  P1_COMPUTE(accA0, accA1, 0);              // tile 0 (scan deferred)
  for (int t = 1; t < 125; t += 2) {
    P1_WAIT(8); P1_STAGE(t + 3);
    P1_COMPUTE(accB0, accB1, t);            // odd tile -> B
    P1_SCAN(accA0, accA1, t - 1);           // scan prev in MFMA issue gaps
    P1_ZERO(accA0, accA1);
    P1_WAIT(8); P1_STAGE(t + 4);
    P1_COMPUTE(accA0, accA1, t + 1);        // even tile -> A
    P1_SCAN(accB0, accB1, t);
    P1_ZERO(accB0, accB1);
  }
  // tiles 0..124 computed (A holds 124); stages issued through 127
  P1_WAIT(8);
  P1_COMPUTE(accB0, accB1, 125); P1_SCAN(accA0, accA1, 124); P1_ZERO(accA0, accA1);
  P1_WAIT(4);
  P1_COMPUTE(accA0, accA1, 126); P1_SCAN(accB0, accB1, 125); P1_ZERO(accB0, accB1);
  P1_WAIT(0);
  P1_COMPUTE(accB0, accB1, 127); P1_SCAN(accA0, accA1, 126);
  P1_SCAN(accB0, accB1, 127);
#undef P1_STAGE
#undef P1_COMPUTE
#undef P1_SCAN
#undef P1_ZERO
#undef P1_WAIT

  // decode own k, then merge half-wave k-partitions (lanes l and l^32 share n)
  int k1d[2];
  #pragma unroll
  for (int s = 0; s < 2; ++s) {
    int x = 4095 - (m1[s] & 4095);
    int kt = x >> 5, kq = (x >> 4) & 1, kr = x & 15;
    k1d[s] = kt * 64 + kq * 32 + (kr & 3) + 8 * (kr >> 2) + 4 * h;
    int o1 = __shfl_xor(m1[s], 32), o2 = __shfl_xor(m2[s], 32);
    int ok1 = __shfl_xor(k1d[s], 32);
    bool take = (o1 > m1[s]) || (o1 == m1[s] && ok1 < k1d[s]);
    int loser = take ? m1[s] : o1;
    if (take) { m1[s] = o1; k1d[s] = ok1; }
    m2[s] = max(m2[s], max(o2, loser));
  }

  __syncthreads();                // all tile reads done; alias lds[0]
  int* rm1 = (int*)&lds[0][0];    // [2][256] each
  int* rk1 = (int*)&lds[0][1024];
  int* rm2 = (int*)&lds[0][2048];
  if (lane < 32) {
    #pragma unroll
    for (int s = 0; s < 2; ++s) {
      int nl = q * 256 + g * 64 + s * 32 + col;
      rm1[nl] = m1[s]; rk1[nl] = k1d[s]; rm2[nl] = m2[s];
    }
  }
  __syncthreads();
  if (tid < 256) {
    int a1 = rm1[tid], a2 = rm2[tid], ak = rk1[tid];
    int c1 = rm1[256 + tid], c2 = rm2[256 + tid], ck = rk1[256 + tid];
    bool take = (c1 > a1) || (c1 == a1 && ck < ak);
    int M1 = take ? c1 : a1;
    int K1 = take ? ck : ak;
    int M2 = max(max(a2, c2), take ? a1 : c1);
    int n = blockIdx.x * 256 + tid;
    int M1a = M1 >> 12, M2a = M2 >> 12;
    // per-row f32 bin width of the ref's distance (~z2) in 2^-24 units:
    // bin = 2^(exp-126); +0.01 bump covers just-below-power-of-2 rows.
    int e = (int)((__float_as_uint(z2s[tid] + 0.01f) >> 23) & 255);
    e = min(max(e, 127), 140);
    int bin = 1 << (e - 126);
    int p = 0;
    if ((M1a - M2a) < (bin * 2 + 128)) {
      int pos = atomicAdd(count, 1);
      if (pos < LIST_CAP) {
        list[pos] = n;
        thrbuf[pos] = M1a - (bin + 256);    // candidate-pass threshold
        refbuf[pos] = 0xFFFFFFFFFFFFFFFFULL;
        p = pos + 1;
      }
    }
    idx1_ws[n] = K1 | (p << 13);
  }
}

// ---------------------------------------------------------------- cand
// Re-run the bit-identical quantized GEMM on flagged (compacted) rows only;
// push every k whose acc >= per-row threshold. K split 4-way across blocks.
__launch_bounds__(512, 2)
__global__ void vq_cand(const float* __restrict__ zg, const u16* __restrict__ ehh,
                        const u16* __restrict__ e2h, const int* __restrict__ count,
                        const int* __restrict__ list, const int* __restrict__ thrbuf,
                        u32* __restrict__ candbuf, int* __restrict__ candcount) {
  __shared__ u16 lds[2][32768];       // 2 x 64 KB: 128 k x 256 d f16, frag-major
  int cnt = *count; if (cnt > LIST_CAP) cnt = LIST_CAP;
  const int rt = blockIdx.x >> 2;     // row tile (64 rows)
  const int ks = blockIdx.x & 3;      // k slice (2048 k)
  if (rt * 64 >= cnt) return;
  const int k0 = ks * 2048;
  const int tid = threadIdx.x, w = tid >> 6, lane = tid & 63;
  const int q = w & 3, g = w >> 2;     // q: k-substrip(0..3), g: row-group(0..1)
  const int col = lane & 31, h = lane >> 5;
  const int ct = rt * 64 + g * 32 + col;         // compact-row index
  const bool valid = ct < cnt;
  const int n_tok = valid ? (list[ct] & (N_TOK - 1)) : 0;
  const int thr = valid ? thrbuf[ct] : 0x7FFFFFFF;

  uint4 zres[16];
  {
    const float4* zp = (const float4*)(zg + (size_t)n_tok * D_DIM);
    #pragma unroll
    for (int c = 0; c < 16; ++c) {
      float4 a = zp[c * 4 + h * 2];
      float4 b2 = zp[c * 4 + h * 2 + 1];
      uint4 u;
      u.x = (u32)f2h(a.x * 64.0f) | ((u32)f2h(a.y * 64.0f) << 16);
      u.y = (u32)f2h(a.z * 64.0f) | ((u32)f2h(a.w * 64.0f) << 16);
      u.z = (u32)f2h(b2.x * 64.0f) | ((u32)f2h(b2.y * 64.0f) << 16);
      u.w = (u32)f2h(b2.z * 64.0f) | ((u32)f2h(b2.w * 64.0f) << 16);
      zres[c] = u;
    }
  }
  uint4 bone = {0, 0, 0, 0};
  if (h == 0) bone.x = 0x3C00u;

  // stage tile 0 of this k-slice: 64 chunks (1 KB each), 8 per wave
  #pragma unroll
  for (int i = 0; i < 8; ++i) {
    int p2 = w * 8 + i, qs = p2 >> 4, cs = p2 & 15;
    gld_lds16(ehh + (size_t)(k0 + qs * 32 + col) * D_DIM + cs * 16 + h * 8,
              &lds[0][qs * 8192 + cs * 512]);
  }

  for (int tK = 0; tK < 16; ++tK) {
    const int b = tK & 1;
    __syncthreads();                  // tile tK staged; tile tK-1 readers done
    if (tK + 1 < 16) {
      const int nb = b ^ 1, kb2 = k0 + (tK + 1) * 128;
      #pragma unroll
      for (int i = 0; i < 8; ++i) {
        int p2 = w * 8 + i, qs = p2 >> 4, cs = p2 & 15;
        gld_lds16(ehh + (size_t)(kb2 + qs * 32 + col) * D_DIM + cs * 16 + h * 8,
                  &lds[nb][qs * 8192 + cs * 512]);
      }
    }
    const int kb = k0 + tK * 128 + q * 32;
    uint4 ea = {0, 0, 0, 0};
    if (h == 0) ea.x = (u32)e2h[kb + col];
    const u16* lb = &lds[b][q * 8192];
    f32x16 acc = {};
    #pragma unroll
    for (int c = 0; c < 16; ++c) {    // same order as phase1 -> bit-identical
      f16x8 a = as_f16x8(*(const uint4*)(lb + c * 512 + lane * 8));
      acc = __builtin_amdgcn_mfma_f32_32x32x16_f16(a, as_f16x8(zres[c]), acc, 0, 0, 0);
    }
    acc = __builtin_amdgcn_mfma_f32_32x32x16_f16(as_f16x8(ea), as_f16x8(bone), acc, 0, 0, 0);
    #pragma unroll
    for (int r = 0; r < 16; ++r) {
      if ((int)acc[r] >= thr) {
        int kg = kb + (r & 3) + 8 * (r >> 2) + 4 * h;
        int pos = atomicAdd(candcount, 1);
        if (pos < CAND_CAP) candbuf[pos] = ((u32)ct << 13) | (u32)kg;
      }
    }
  }
}

// ---------------------------------------------------------------- refine2
// Per candidate: val = fl32(fl32(z2+e2) - 2*fl32(dot)) exactly as np-f32 does;
// key = (val_bits<<13)|k, atomicMin -> min val, tie -> lowest k (first-occurrence).
__global__ void vq_refine2(const float* __restrict__ zg, const float* __restrict__ emb,
                           const float* __restrict__ z2f, const float* __restrict__ e2f,
                           const int* __restrict__ list, const int* __restrict__ candcount,
                           const u32* __restrict__ candbuf, u64* __restrict__ refbuf) {
  const int w = threadIdx.x >> 6, lane = threadIdx.x & 63;
  int ccnt = *candcount; if (ccnt > CAND_CAP) ccnt = CAND_CAP;
  for (int i = blockIdx.x * 4 + w; i < ccnt; i += gridDim.x * 4) {
    const u32 rec = candbuf[i];
    const int p = (int)(rec >> 13), k = (int)(rec & 8191u);
    const int n = list[p] & (N_TOK - 1);
    float4 zv = ((const float4*)(zg + (size_t)n * D_DIM))[lane];
    float4 ev = ((const float4*)(emb + (size_t)k * D_DIM))[lane];
    double s = (double)zv.x * ev.x + (double)zv.y * ev.y +
               (double)zv.z * ev.z + (double)zv.w * ev.w;
    #pragma unroll
    for (int off = 32; off > 0; off >>= 1) s += __shfl_down(s, off);
    if (lane == 0) {
      float S = z2f[n] + e2f[k];           // fl32(z2+e2)
      float val = S - 2.0f * (float)s;     // fl32(S - 2*fl32(dot))
      u64 key = ((u64)__float_as_uint(val) << 13) | (u64)k;
      atomicMin((unsigned long long*)(refbuf + p), (unsigned long long)key);
    }
  }
}

// ---------------------------------------------------------------- gather
// f32 outputs: quantized = straight_through = emb[idx]; indices as f32.
__global__ void vq_gather(const float* __restrict__ emb, const int* __restrict__ idx1_ws,
                          const u64* __restrict__ refbuf, float* __restrict__ out) {
  const int w = threadIdx.x >> 6, lane = threadIdx.x & 63;
  const int n = blockIdx.x * 4 + w;
  const int enc = idx1_ws[n];
  int idx = enc & 8191;
  const int p = enc >> 13;
  if (p > 0) {
    u64 rb = refbuf[p - 1];
    if (rb != 0xFFFFFFFFFFFFFFFFULL) idx = (int)(rb & 8191ULL);
  }
  float4 v = ((const float4*)(emb + (size_t)idx * D_DIM))[lane];
  float4* o = (float4*)out;
  o[(size_t)n * 64 + lane] = v;
  o[(size_t)4194304 + (size_t)n * 64 + lane] = v;         // + N*D (float4 units)
  if (lane == 0) out[(size_t)33554432 + n] = (float)idx;  // + 2*N*D (float units)
}

extern "C" void kernel_launch(void* const* d_in, const int* in_sizes, int n_in,
                              void* d_out, int out_size, void* d_ws, size_t ws_size,
                              hipStream_t stream) {
  const float* z   = (const float*)d_in[0];
  const float* emb = (const float*)d_in[1];
  char* ws = (char*)d_ws;
  // Workspace layout (bytes), total 5,029,896 — within the 5.38 MB envelope.
  u16*   ehh       = (u16*)(ws);                  // [0        .. 4194304)
  float* e2f       = (float*)(ws + 4194304);      // [4194304  .. 4227072)
  u16*   e2h       = (u16*)(ws + 4227072);        // [4227072  .. 4243456)
  float* z2f       = (float*)(ws + 4243456);      // [4243456  .. 4505600)
  int*   idx1_ws   = (int*)(ws + 4505600);        // [4505600  .. 4767744)
  u64*   refbuf    = (u64*)(ws + 4767744);        // [4767744  .. 4866048)  12288*8
  int*   list      = (int*)(ws + 4866048);        // [4866048  .. 4915200)  12288*4
  int*   thrbuf    = (int*)(ws + 4915200);        // [4915200  .. 4964352)  12288*4
  u32*   candbuf   = (u32*)(ws + 4964352);        // [4964352  .. 5029888)  16384*4
  int*   count     = (int*)(ws + 5029888);        // [5029888  .. 5029892)
  int*   candcount = (int*)(ws + 5029892);        // [5029892  .. 5029896)

  vq_prep   <<<K_EMB / 4, 256, 0, stream>>>(emb, ehh, e2f, e2h, count, candcount);
  vq_phase1 <<<N_TOK / 256, 512, 0, stream>>>(z, ehh, e2h, z2f, idx1_ws, thrbuf,
                                              refbuf, list, count);
  vq_cand   <<<768, 512, 0, stream>>>(z, ehh, e2h, count, list, thrbuf,
                                      candbuf, candcount);
  vq_refine2<<<512, 256, 0, stream>>>(z, emb, z2f, e2f, list, candcount,
                                      candbuf, refbuf);
  vq_gather <<<N_TOK / 4, 256, 0, stream>>>(emb, idx1_ws, refbuf, (float*)d_out);
}